// Round 1
// baseline (413.203 us; speedup 1.0000x reference)
//
#include <hip/hip_runtime.h>
#include <math.h>

#define B_TOT 4096
#define IC 64
#define OC 16
#define DIM 64
#define G 8              // batch elems per block in iteration kernel
#define NBLK (B_TOT / G) // 512

// ---------------------------------------------------------------------------
// Setup: W_S_t[m][f][i] = W_S[i][m][f]; B_S_t[m][i]; cb=bu+bi; db=sum_m bi;
// eb[i] = sum_m(bu+bi)/16 - db  (phi for uniform R=1/16)
// ---------------------------------------------------------------------------
__global__ void kSetup(const float* __restrict__ WS, const float* __restrict__ BS,
                       const float* __restrict__ bu, const float* __restrict__ bi_,
                       float* __restrict__ WSt, float* __restrict__ BSt,
                       float* __restrict__ cb, float* __restrict__ db,
                       float* __restrict__ eb)
{
    int gt = blockIdx.x * 256 + threadIdx.x; // 0..16383
#pragma unroll
    for (int j = 0; j < 4; j++) {
        int e = gt + j * 16384;      // 0..65535
        int m = e >> 12;
        int rem = e & 4095;
        int f = rem >> 6;
        int i = rem & 63;
        WSt[e] = WS[((size_t)i * OC + m) * DIM + f];
    }
    if (gt < OC * IC) { // B_S_t[m][i]
        int m = gt >> 6, i = gt & 63;
        BSt[gt] = BS[i * OC + m];
    }
    if (gt < IC * OC) { // cb[i][m], same flat layout as bu/bi
        cb[gt] = bu[gt] + bi_[gt];
    }
    if (gt < IC) {
        float sc = 0.f, sd = 0.f;
        for (int m = 0; m < OC; m++) {
            sc += bu[gt * OC + m] + bi_[gt * OC + m];
            sd += bi_[gt * OC + m];
        }
        db[gt] = sd;
        eb[gt] = sc * (1.0f / 16.0f) - sd;
    }
}

// ---------------------------------------------------------------------------
// Kernel A: temp_F[b][i][h] = (x[b][i][:] @ W_F1[i]) * 0.125
//           f_a[b][i] = sigmoid( dot(x[b][i][:], W_A[i]) * 0.125 + B_A[i] )
// grid (64 b-tiles, 64 i), block 256.  64x64 output tile, 4x4 reg tiling.
// ---------------------------------------------------------------------------
__global__ __launch_bounds__(256, 4)
void kA(const float* __restrict__ x, const float* __restrict__ W_F1,
        const float* __restrict__ W_A, const float* __restrict__ B_A,
        float* __restrict__ tF, float* __restrict__ fa)
{
    __shared__ float Xs[64][68]; // pad 68: float4-aligned, 2-way-max bank alias
    __shared__ float Ws[64][64];
    __shared__ float WAs[64];
    const int i = blockIdx.y;
    const int b0 = blockIdx.x * 64;
    const int t = threadIdx.x;

    { // stage X tile: thread -> row bl=t>>2, 16 cols at (t&3)*16
        int bl = t >> 2, c0 = (t & 3) * 16;
        const float* src = x + ((size_t)(b0 + bl) * IC + i) * DIM + c0;
        float4 v0 = ((const float4*)src)[0];
        float4 v1 = ((const float4*)src)[1];
        float4 v2 = ((const float4*)src)[2];
        float4 v3 = ((const float4*)src)[3];
        float* dst = &Xs[bl][c0];
        ((float4*)dst)[0] = v0; ((float4*)dst)[1] = v1;
        ((float4*)dst)[2] = v2; ((float4*)dst)[3] = v3;
    }
    { // stage W_F1[i]
        int f = t >> 2, c0 = (t & 3) * 16;
        const float* src = W_F1 + ((size_t)i * DIM + f) * DIM + c0;
        float4 v0 = ((const float4*)src)[0];
        float4 v1 = ((const float4*)src)[1];
        float4 v2 = ((const float4*)src)[2];
        float4 v3 = ((const float4*)src)[3];
        float* dst = &Ws[f][c0];
        ((float4*)dst)[0] = v0; ((float4*)dst)[1] = v1;
        ((float4*)dst)[2] = v2; ((float4*)dst)[3] = v3;
    }
    if (t < 64) WAs[t] = W_A[i * 64 + t];
    __syncthreads();

    const int tr = t >> 4, tc = t & 15;
    float ax[4][4]; // acc[row][col]
#pragma unroll
    for (int r = 0; r < 4; r++)
#pragma unroll
        for (int c = 0; c < 4; c++) ax[r][c] = 0.f;

#pragma unroll 8
    for (int k = 0; k < 64; k++) {
        float4 w = *(const float4*)&Ws[k][tc * 4];
#pragma unroll
        for (int r = 0; r < 4; r++) {
            float a = Xs[tr * 4 + r][k];
            ax[r][0] += a * w.x; ax[r][1] += a * w.y;
            ax[r][2] += a * w.z; ax[r][3] += a * w.w;
        }
    }
#pragma unroll
    for (int r = 0; r < 4; r++) {
        float4 o;
        o.x = ax[r][0] * 0.125f; o.y = ax[r][1] * 0.125f;
        o.z = ax[r][2] * 0.125f; o.w = ax[r][3] * 0.125f;
        *(float4*)&tF[((size_t)(b0 + tr * 4 + r) * IC + i) * DIM + tc * 4] = o;
    }
    if (t < 64) { // f_a for this (b-tile, i)
        float acc = 0.f;
        for (int f = 0; f < 64; f++) acc += Xs[t][f] * WAs[f];
        float ae = acc * 0.125f + B_A[i];
        fa[(size_t)(b0 + t) * IC + i] = 1.0f / (1.0f + expf(-ae));
    }
}

// ---------------------------------------------------------------------------
// Kernel B: one routing iteration, fused. 512 blocks x 256 thr, G=8 b/block.
// ---------------------------------------------------------------------------
__global__ __launch_bounds__(256, 2)
void kB(const float* __restrict__ x, const float* __restrict__ tF,
        const float* __restrict__ fa, const float* __restrict__ cb,
        const float* __restrict__ db, const float* __restrict__ eb,
        float* __restrict__ R,
        const float* __restrict__ W_F2, const float* __restrict__ B_F2,
        const float* __restrict__ W_G1,
        const float* __restrict__ W_G2, const float* __restrict__ B_G2,
        const float* __restrict__ gam, const float* __restrict__ bet,
        const float* __restrict__ WSt, const float* __restrict__ BSt,
        float* __restrict__ out, const int first_iter, const int last_iter)
{
    __shared__ float phi_s[G][IC];           // 2 KB
    __shared__ float s_s[G][DIM];            // 2 KB
    __shared__ float rows[4][2][G][DIM];     // 16 KB (xnorm then temp_G, per wave-half)
    __shared__ float xh_cons[G * IC * 17];   // 34.8 KB (xhat view, then consistency view)

    const int t = threadIdx.x;
    const int b0 = blockIdx.x * G;
    const int wave = t >> 6;
    const int lane = t & 63;
    const int half = lane >> 5;
    const int c = lane & 31;
    const int col2 = c * 2;

    // ---- phase 0: phi_sum[g][i] ----
    for (int p = t; p < G * IC; p += 256) {
        int g = p >> 6, i = p & 63;
        size_t bi = (size_t)(b0 + g) * IC + i;
        float f = fa[bi];
        float ph;
        if (first_iter) {
            ph = f * eb[i];
        } else {
            const float4* Rp = (const float4*)(R + bi * OC);
            const float4* cp = (const float4*)(cb + i * OC);
            float acc = 0.f;
#pragma unroll
            for (int q = 0; q < 4; q++) {
                float4 r4 = Rp[q]; float4 c4 = cp[q];
                acc += r4.x * c4.x + r4.y * c4.y + r4.z * c4.z + r4.w * c4.w;
            }
            ph = f * (acc - db[i]);
        }
        phi_s[g][i] = ph;
    }
    __syncthreads();

    // ---- phase 1: s[g][h] = sum_i phi[g][i] * tF[b][i][h] ----
    {
        int g = t >> 5, h = (t & 31) * 2;
        const float* tfp = tF + ((size_t)(b0 + g) * IC) * DIM + h;
        float a0 = 0.f, a1 = 0.f;
#pragma unroll 8
        for (int i = 0; i < IC; i++) {
            float2 v = *(const float2*)(tfp + (size_t)i * DIM);
            float p = phi_s[g][i];
            a0 += p * v.x; a1 += p * v.y;
        }
        *(float2*)&s_s[g][h] = make_float2(a0, a1);
    }
    __syncthreads();

    const float gam0 = gam[col2], gam1 = gam[col2 + 1];
    const float bet0 = bet[col2], bet1 = bet[col2 + 1];

    // ---- m-loop: each wave owns 4 m's, processed 2-at-a-time via halves ----
    for (int pass = 0; pass < 2; pass++) {
        const int m = wave * 4 + pass * 2 + half;

        // phase 2: x_out[g][m][col2..col2+1]
        float xo0[G], xo1[G];
        {
            const float* wp = W_F2 + ((size_t)m * DIM) * DIM + col2;
#pragma unroll
            for (int g = 0; g < G; g++) { xo0[g] = 0.f; xo1[g] = 0.f; }
#pragma unroll 8
            for (int h = 0; h < DIM; h++) {
                float2 w = *(const float2*)(wp + (size_t)h * DIM);
#pragma unroll
                for (int g = 0; g < G; g++) {
                    float sv = s_s[g][h];
                    xo0[g] += sv * w.x; xo1[g] += sv * w.y;
                }
            }
            float2 bf = *(const float2*)(B_F2 + m * DIM + col2);
#pragma unroll
            for (int g = 0; g < G; g++) { xo0[g] += bf.x; xo1[g] += bf.y; }
        }
        if (last_iter) {
#pragma unroll
            for (int g = 0; g < G; g++)
                *(float2*)&out[((size_t)(b0 + g) * OC + m) * DIM + col2] =
                    make_float2(xo0[g], xo1[g]);
        }
        // LayerNorm in-register (row lives across the 32 lanes of this half)
#pragma unroll
        for (int g = 0; g < G; g++) {
            float sum = xo0[g] + xo1[g];
            float sq = xo0[g] * xo0[g] + xo1[g] * xo1[g];
#pragma unroll
            for (int k = 1; k <= 16; k <<= 1) {
                sum += __shfl_xor(sum, k);
                sq  += __shfl_xor(sq, k);
            }
            float mu = sum * (1.0f / 64.0f);
            float var = sq * (1.0f / 64.0f) - mu * mu;
            float rs = 1.0f / sqrtf(var + 1e-5f);
            float n0 = (xo0[g] - mu) * rs * gam0 + bet0;
            float n1 = (xo1[g] - mu) * rs * gam1 + bet1;
            *(float2*)&rows[wave][half][g][col2] = make_float2(n0, n1);
        }
        __syncthreads();

        // phase 3: temp_G[g][m][col2..] = sum_d xnorm[g][m][d] * W_G1[d][col2..]
        float tg0[G], tg1[G];
        {
            const float* wp = W_G1 + col2;
#pragma unroll
            for (int g = 0; g < G; g++) { tg0[g] = 0.f; tg1[g] = 0.f; }
#pragma unroll 8
            for (int d = 0; d < DIM; d++) {
                float2 w = *(const float2*)(wp + (size_t)d * DIM);
#pragma unroll
                for (int g = 0; g < G; g++) {
                    float xn = rows[wave][half][g][d];
                    tg0[g] += xn * w.x; tg1[g] += xn * w.y;
                }
            }
        }
        __syncthreads();
#pragma unroll
        for (int g = 0; g < G; g++)
            *(float2*)&rows[wave][half][g][col2] = make_float2(tg0[g], tg1[g]);
        __syncthreads();

        // phase 4: xhat[g][m][col2..] = sum_h tG * W_G2[m][h][col2..] + B_G2
        {
            const float* wp = W_G2 + ((size_t)m * DIM) * DIM + col2;
            float2 bg = *(const float2*)(B_G2 + m * DIM + col2);
            float xh0[G], xh1[G];
#pragma unroll
            for (int g = 0; g < G; g++) { xh0[g] = bg.x; xh1[g] = bg.y; }
#pragma unroll 8
            for (int h = 0; h < DIM; h++) {
                float2 w = *(const float2*)(wp + (size_t)h * DIM);
#pragma unroll
                for (int g = 0; g < G; g++) {
                    float tg = rows[wave][half][g][h];
                    xh0[g] += tg * w.x; xh1[g] += tg * w.y;
                }
            }
#pragma unroll
            for (int g = 0; g < G; g++)
                *(float2*)&xh_cons[((g * OC + m) * DIM) + col2] =
                    make_float2(xh0[g], xh1[g]);
        }
        __syncthreads();
    }

    // ---- phase 5: consistency[g][i][m] = sum_f x*xhat*W_S + B_S ----
    {
        const int i = lane;
        float acc[G][4];
#pragma unroll
        for (int k = 0; k < 4; k++) {
            float bs = BSt[(wave * 4 + k) * IC + i];
#pragma unroll
            for (int g = 0; g < G; g++) acc[g][k] = bs;
        }
        for (int f0 = 0; f0 < DIM; f0 += 8) {
            float wreg[4][8];
#pragma unroll
            for (int k = 0; k < 4; k++) {
                const float* wp = WSt + (((size_t)(wave * 4 + k) * DIM) + f0) * IC + i;
#pragma unroll
                for (int ff = 0; ff < 8; ff++) wreg[k][ff] = wp[ff * IC];
            }
#pragma unroll
            for (int g = 0; g < G; g++) {
                const float* xp = x + ((size_t)(b0 + g) * IC + i) * DIM + f0;
                float4 xa = *(const float4*)(xp);
                float4 xb = *(const float4*)(xp + 4);
                float xr[8] = {xa.x, xa.y, xa.z, xa.w, xb.x, xb.y, xb.z, xb.w};
#pragma unroll
                for (int k = 0; k < 4; k++) {
                    const float* hp = &xh_cons[(g * OC + wave * 4 + k) * DIM + f0];
                    float4 ha = *(const float4*)(hp);
                    float4 hb = *(const float4*)(hp + 4);
                    float hr[8] = {ha.x, ha.y, ha.z, ha.w, hb.x, hb.y, hb.z, hb.w};
#pragma unroll
                    for (int ff = 0; ff < 8; ff++)
                        acc[g][k] += xr[ff] * hr[ff] * wreg[k][ff];
                }
            }
        }
        __syncthreads(); // everyone done READING xhat view before overwrite
#pragma unroll
        for (int k = 0; k < 4; k++)
#pragma unroll
            for (int g = 0; g < G; g++)
                xh_cons[(g * IC + i) * 17 + wave * 4 + k] = acc[g][k];
    }
    __syncthreads();

    // ---- softmax over m -> R (skipped on last iteration) ----
    if (!last_iter) {
        for (int p = t; p < G * IC; p += 256) {
            int g = p >> 6, i = p & 63;
            float v[16];
            float mx = -1e30f;
#pragma unroll
            for (int m = 0; m < OC; m++) {
                v[m] = xh_cons[(g * IC + i) * 17 + m];
                mx = fmaxf(mx, v[m]);
            }
            float sum = 0.f;
#pragma unroll
            for (int m = 0; m < OC; m++) {
                v[m] = expf(v[m] - mx);
                sum += v[m];
            }
            float inv = 1.0f / sum;
            float* Rp = R + ((size_t)(b0 + g) * IC + i) * OC;
#pragma unroll
            for (int q = 0; q < 4; q++)
                ((float4*)Rp)[q] = make_float4(v[q * 4] * inv, v[q * 4 + 1] * inv,
                                               v[q * 4 + 2] * inv, v[q * 4 + 3] * inv);
        }
    }
}

// ---------------------------------------------------------------------------
extern "C" void kernel_launch(void* const* d_in, const int* in_sizes, int n_in,
                              void* d_out, int out_size, void* d_ws, size_t ws_size,
                              hipStream_t stream)
{
    const float* x    = (const float*)d_in[0];
    const float* W_A  = (const float*)d_in[1];
    const float* B_A  = (const float*)d_in[2];
    const float* W_F1 = (const float*)d_in[3];
    const float* W_F2 = (const float*)d_in[4];
    const float* B_F2 = (const float*)d_in[5];
    const float* W_G1 = (const float*)d_in[6];
    const float* W_G2 = (const float*)d_in[7];
    const float* B_G2 = (const float*)d_in[8];
    const float* gam  = (const float*)d_in[9];
    const float* bet  = (const float*)d_in[10];
    const float* W_S  = (const float*)d_in[11];
    const float* B_S  = (const float*)d_in[12];
    const float* bu   = (const float*)d_in[13];
    const float* bi_  = (const float*)d_in[14];

    float* ws  = (float*)d_ws;
    float* tF  = ws;                                   // 4096*64*64
    float* fa  = tF + (size_t)B_TOT * IC * DIM;        // 4096*64
    float* R   = fa + (size_t)B_TOT * IC;              // 4096*64*16
    float* WSt = R + (size_t)B_TOT * IC * OC;          // 16*64*64
    float* BSt = WSt + (size_t)OC * DIM * IC;          // 16*64
    float* cb  = BSt + OC * IC;                        // 64*16
    float* db  = cb + IC * OC;                         // 64
    float* eb  = db + IC;                              // 64
    float* out = (float*)d_out;

    kSetup<<<64, 256, 0, stream>>>(W_S, B_S, bu, bi_, WSt, BSt, cb, db, eb);
    kA<<<dim3(64, 64), 256, 0, stream>>>(x, W_F1, W_A, B_A, tF, fa);
    for (int it = 0; it < 3; ++it)
        kB<<<NBLK, 256, 0, stream>>>(x, tF, fa, cb, db, eb, R,
                                     W_F2, B_F2, W_G1, W_G2, B_G2, gam, bet,
                                     WSt, BSt, out, it == 0 ? 1 : 0, it == 2 ? 1 : 0);
}